// Round 7
// baseline (1581.178 us; speedup 1.0000x reference)
//
#include <hip/hip_runtime.h>

// OnlineLSTM: B=8192, T=2048, I=1, H=50.
// R12: WAVE-SPECIALIZED ANTI-PHASE PIPELINE. Ledger: R3/R11 (2 same-phase
// waves/SIMD) stall ~620 cyc/step; R10 (zig-zag, 1 wave/SIMD) proved phase
// overlap cuts per-interval stall but losing the 2nd hardware wave stream
// costs more; R4 proved same-phase ILP hides nothing. This kernel gets BOTH:
// 512-thread block = 32 rows as two 16-row groups; waves 0-3 = group A,
// waves 4-7 = group B, offset by one barrier interval:
//   interval P: GA: read hA(t)->MFMA->zA   | GB: gates(zB)->store hB(t+1)
//   interval Q: GA: gates(zA)->store hA(t+1) | GB: read hB(t+1)->MFMA->zB
// Round-robin wave->SIMD puts wave i and i+4 on SIMD i: every SIMD hosts one
// gates-phase wave (VALU/trans, setprio 1) and one MFMA-phase wave (LDS +
// matrix pipe) every interval — anti-phase BY CONSTRUCTION, cannot collapse.
// z stays in registers across the barrier; single-buffered LDS per group
// (store->read always barrier-separated). Per-row math bit-identical to the
// 1255-us R11: packed-fp32 gates, K padded 50->64 (k=50 x_t, k=51 1.0),
// weights prescaled -log2e (i,f,o) / +2log2e (g), x-prefetch depth 2.
// Grid 256 = 1 block/CU (8 waves/CU = 2/SIMD).

#define HID   50
#define NSTEP 2048
#define BPB   32     // 2 groups x 16 rows
#define HSTR  72     // fp16 elems per hbuf row

typedef _Float16 half8   __attribute__((ext_vector_type(8)));
typedef float    float4v __attribute__((ext_vector_type(4)));
typedef float    float2v __attribute__((ext_vector_type(2)));

__device__ __forceinline__ float2v lo2(float4v v) { float2v r; r[0] = v[0]; r[1] = v[1]; return r; }
__device__ __forceinline__ float2v hi2(float4v v) { float2v r; r[0] = v[2]; r[1] = v[3]; return r; }

__device__ __forceinline__ float2v exp2v(float2v x) {
    float2v r;
    r[0] = __builtin_amdgcn_exp2f(x[0]);
    r[1] = __builtin_amdgcn_exp2f(x[1]);
    return r;
}

// Two rows at once. zi,zf,zo = -log2e * raw; zg = 2log2e * raw (prescaled in
// weights). Returns h pair, updates c pair. Packed fp32 algebra; one rcp per
// division pair via rcp(D0*D1) * swapped-D trick.
__device__ __forceinline__ float2v gate_pairs2(float2v zi, float2v zf, float2v zg,
                                               float2v zo, float2v& c) {
    float2v ei = exp2v(zi);      // e^{-i_raw}
    float2v ef = exp2v(zf);
    float2v Eg = exp2v(zg);      // e^{2 g_raw}
    float2v eo = exp2v(zo);
    float2v t1  = (1.0f + ei) * (1.0f + Eg);
    float2v pf  = 1.0f + ef;
    float2v num = c * t1 + pf * (Eg - 1.0f);
    float2v D   = t1 * pf;
    float   rP  = __builtin_amdgcn_rcpf(D[0] * D[1]);
    float2v Dsw; Dsw[0] = D[1]; Dsw[1] = D[0];
    c = num * Dsw * rP;
    float2v a = 2.8853900817779268f * c;     // 2*log2e * c
    a[0] = fminf(fmaxf(a[0], -24.0f), 24.0f);
    a[1] = fminf(fmaxf(a[1], -24.0f), 24.0f);
    float2v Ec  = exp2v(a);                  // e^{2c}
    float2v den = (1.0f + eo) * (1.0f + Ec);
    float   rQ  = __builtin_amdgcn_rcpf(den[0] * den[1]);
    float2v dsw; dsw[0] = den[1]; dsw[1] = den[0];
    return (Ec - 1.0f) * dsw * rQ;           // sigma(o) * tanh(c)
}

__global__ __launch_bounds__(512, 1) void lstm_fused(
    const float* __restrict__ x,
    const float* __restrict__ W_ih,
    const float* __restrict__ W_hh,
    const float* __restrict__ b_ih,
    const float* __restrict__ b_hh,
    const float* __restrict__ W_lin,
    const float* __restrict__ b_lin,
    float* __restrict__ out)
{
    // [group][row][k] — single buffer per group (store->read barrier-separated)
    __shared__ __align__(16) _Float16 hbuf[2][16][HSTR];

    const int tid  = threadIdx.x;
    const int wave = tid >> 6;
    const int grp  = wave >> 2;          // 0 = group A (waves 0-3), 1 = B (4-7)
    const int wv   = wave & 3;           // j-tile within group
    const int lane = tid & 63;
    const int col  = lane & 15;
    const int quad = lane >> 4;
    const int bb   = blockIdx.x * BPB;
    const int b0g  = bb + grp * 16;      // my group's first batch row
    const int j    = wv * 16 + col;

    // ---- init h buffers: zeros, x_0 at col 50, 1.0 at col 51 ----
    for (int i = tid; i < 2 * 16 * HSTR; i += 512)
        (&hbuf[0][0][0])[i] = (_Float16)0.0f;
    __syncthreads();
    if (tid < BPB) {
        int g = tid >> 4, r = tid & 15;
        hbuf[g][r][HID]     = (_Float16)x[(size_t)(bb + tid) * NSTEP];
        hbuf[g][r][HID + 1] = (_Float16)1.0f;
    }

    // ---- persistent B fragments, prescaled per gate (same for both groups) ----
    const float LOG2E = 1.4426950408889634f;
    half8 bfrag[4][2];
    for (int g = 0; g < 4; ++g) {
        const float sc = (g == 2) ? (2.0f * LOG2E) : (-LOG2E);
        for (int kt = 0; kt < 2; ++kt) {
            half8 f;
            #pragma unroll
            for (int jj = 0; jj < 8; ++jj) {
                int k = kt * 32 + quad * 8 + jj;
                float v = 0.0f;
                if (j < HID) {
                    int row = g * HID + j;
                    if (k < HID)           v = W_hh[row * HID + k];
                    else if (k == HID)     v = W_ih[row];
                    else if (k == HID + 1) v = b_ih[row] + b_hh[row];
                }
                f[jj] = (_Float16)(v * sc);
            }
            bfrag[g][kt] = f;
        }
    }

    float2v c01 = {0.f, 0.f};
    float2v c23 = {0.f, 0.f};
    float4v z0, z1, z2, z3;
    const bool xloader = (wv == 3) && (quad == 0);
    const float* xrow = x + (size_t)(b0g + col) * NSTEP;
    const float4v Z4 = {0.f, 0.f, 0.f, 0.f};

    // depth-2 x prefetch: preload x[1] for the first gates phase
    float xn_reg = 0.f;
    if (xloader)
        xn_reg = xrow[1];

    __syncthreads();

#define MFMA_PHASE()                                                             \
    {                                                                            \
        const _Float16* arow = &hbuf[grp][col][0];                               \
        half8 a0 = *(const half8*)(arow + quad * 8);                             \
        half8 a1 = *(const half8*)(arow + 32 + quad * 8);                        \
        z0 = __builtin_amdgcn_mfma_f32_16x16x32_f16(a0, bfrag[0][0], Z4, 0, 0, 0); \
        z1 = __builtin_amdgcn_mfma_f32_16x16x32_f16(a0, bfrag[1][0], Z4, 0, 0, 0); \
        z2 = __builtin_amdgcn_mfma_f32_16x16x32_f16(a0, bfrag[2][0], Z4, 0, 0, 0); \
        z3 = __builtin_amdgcn_mfma_f32_16x16x32_f16(a0, bfrag[3][0], Z4, 0, 0, 0); \
        z0 = __builtin_amdgcn_mfma_f32_16x16x32_f16(a1, bfrag[0][1], z0, 0, 0, 0); \
        z1 = __builtin_amdgcn_mfma_f32_16x16x32_f16(a1, bfrag[1][1], z1, 0, 0, 0); \
        z2 = __builtin_amdgcn_mfma_f32_16x16x32_f16(a1, bfrag[2][1], z2, 0, 0, 0); \
        z3 = __builtin_amdgcn_mfma_f32_16x16x32_f16(a1, bfrag[3][1], z3, 0, 0, 0); \
    }

#define GATES_PHASE(T)                                                           \
    {                                                                            \
        if (xloader)                                                             \
            hbuf[grp][col][HID] = (_Float16)xn_reg;                              \
        float xn_new = 0.f;                                                      \
        if (xloader) {                                                           \
            int tt = (T) + 2;                                                    \
            if (tt > NSTEP - 1) tt = NSTEP - 1;                                  \
            xn_new = xrow[tt];                                                   \
        }                                                                        \
        __builtin_amdgcn_s_setprio(1);                                           \
        float2v h01 = gate_pairs2(lo2(z0), lo2(z1), lo2(z2), lo2(z3), c01);      \
        if (j < HID) {                                                           \
            hbuf[grp][quad * 4 + 0][j] = (_Float16)h01[0];                       \
            hbuf[grp][quad * 4 + 1][j] = (_Float16)h01[1];                       \
        }                                                                        \
        float2v h23 = gate_pairs2(hi2(z0), hi2(z1), hi2(z2), hi2(z3), c23);      \
        if (j < HID) {                                                           \
            hbuf[grp][quad * 4 + 2][j] = (_Float16)h23[0];                       \
            hbuf[grp][quad * 4 + 3][j] = (_Float16)h23[1];                       \
        }                                                                        \
        __builtin_amdgcn_s_setprio(0);                                           \
        xn_reg = xn_new;                                                         \
    }

    // ---- prologue: group B computes zB(0) so it enters interval P in gates ----
    if (grp == 1) {
        MFMA_PHASE()
    }
    __syncthreads();

    // Invariant at top of iteration t:
    //   hbuf[0] = hA(t)+xA(t), hbuf[1] = hB(t)+xB(t), zB = z_B(t) (GB regs).
    // P: GA: zA = z_A(t) from hbuf[0]   | GB: gates zB -> store hB(t+1)
    // Q: GA: gates zA -> store hA(t+1)  | GB: zB = z_B(t+1) from hbuf[1]
    for (int t = 0; t < NSTEP; ++t) {
        if (grp == 0) {
            MFMA_PHASE()
        } else {
            GATES_PHASE(t)
        }
        __syncthreads();
        if (grp == 0) {
            GATES_PHASE(t)
        } else {
            MFMA_PHASE()
        }
        __syncthreads();
    }
#undef MFMA_PHASE
#undef GATES_PHASE

    // ---- epilogue: out[b] = h_last . W_lin + b_lin ----
    if (tid < BPB) {
        int g = tid >> 4, r = tid & 15;
        float s = b_lin[0];
        for (int k = 0; k < HID; ++k)
            s += (float)hbuf[g][r][k] * W_lin[k];
        out[bb + tid] = s;
    }
}

extern "C" void kernel_launch(void* const* d_in, const int* in_sizes, int n_in,
                              void* d_out, int out_size, void* d_ws, size_t ws_size,
                              hipStream_t stream) {
    const float* x     = (const float*)d_in[0];
    const float* W_ih  = (const float*)d_in[1];
    const float* W_hh  = (const float*)d_in[2];
    const float* b_ih  = (const float*)d_in[3];
    const float* b_hh  = (const float*)d_in[4];
    const float* W_lin = (const float*)d_in[5];
    const float* b_lin = (const float*)d_in[6];
    float* outp = (float*)d_out;
    dim3 grid(8192 / BPB), block(512);
    hipLaunchKernelGGL(lstm_fused, grid, block, 0, stream,
                       x, W_ih, W_hh, b_ih, b_hh, W_lin, b_lin, outp);
}

// Round 9
// 1278.147 us; speedup vs baseline: 1.2371x; 1.2371x over previous
//
#include <hip/hip_runtime.h>

// OnlineLSTM: B=8192, T=2048, I=1, H=50.
// R13 = R11 (best: 1255 us; 2 blocks/CU, same-phase, packed-fp32 gates,
// x-prefetch depth 2, store/gate interleave, gate setprio) + two stall
// removers, everything else bit-identical:
//  (1) lgkmcnt-only barrier: __syncthreads() drains vmcnt(0) too, so the
//      xloader wave's in-flight x[t+2] global load (~200cyc L2) can make it
//      the barrier laggard every step. The loaded value isn't needed until
//      the NEXT step's store (compiler guards that use with its own vmcnt
//      wait), so the barrier only needs lgkmcnt(0) for LDS visibility.
//  (2) persistent asymmetric block priority: R3 proved the one-shot s_sleep
//      stagger decays into lockstep. Odd blocks now run at prio 1 for the
//      whole loop (even blocks keep prio 1 only inside gates). Odd always
//      wins issue arbitration -> finishes its chain early -> parks at its
//      barrier while even runs in the freed slots: a standing anti-phase
//      enforced by the arbiter, not by decaying initial conditions.
// Ledger (R4/R10/R12): every structural rearrangement (same-phase ILP,
// zig-zag 1-wave, wave-specialized anti-phase) regressed; only issue cuts
// and stall-component removal on the 2-waves/SIMD structure have won.
// [Resubmit: Round-8 bench hit GPUAcquisitionTimeout; kernel unmeasured.]

#define HID   50
#define NSTEP 2048
#define BPB   16
#define HSTR  72     // fp16 elems per hbuf row

typedef _Float16 half8   __attribute__((ext_vector_type(8)));
typedef float    float4v __attribute__((ext_vector_type(4)));
typedef float    float2v __attribute__((ext_vector_type(2)));

__device__ __forceinline__ float2v lo2(float4v v) { float2v r; r[0] = v[0]; r[1] = v[1]; return r; }
__device__ __forceinline__ float2v hi2(float4v v) { float2v r; r[0] = v[2]; r[1] = v[3]; return r; }

__device__ __forceinline__ float2v exp2v(float2v x) {
    float2v r;
    r[0] = __builtin_amdgcn_exp2f(x[0]);
    r[1] = __builtin_amdgcn_exp2f(x[1]);
    return r;
}

// Two rows at once. zi,zf,zo = -log2e * raw; zg = 2log2e * raw (prescaled in
// weights). Returns h pair, updates c pair. Packed fp32 algebra; one rcp per
// division pair via rcp(D0*D1) * swapped-D trick.
__device__ __forceinline__ float2v gate_pairs2(float2v zi, float2v zf, float2v zg,
                                               float2v zo, float2v& c) {
    float2v ei = exp2v(zi);      // e^{-i_raw}
    float2v ef = exp2v(zf);
    float2v Eg = exp2v(zg);      // e^{2 g_raw}
    float2v eo = exp2v(zo);
    float2v t1  = (1.0f + ei) * (1.0f + Eg);
    float2v pf  = 1.0f + ef;
    float2v num = c * t1 + pf * (Eg - 1.0f);
    float2v D   = t1 * pf;
    float   rP  = __builtin_amdgcn_rcpf(D[0] * D[1]);
    float2v Dsw; Dsw[0] = D[1]; Dsw[1] = D[0];
    c = num * Dsw * rP;
    float2v a = 2.8853900817779268f * c;     // 2*log2e * c
    a[0] = fminf(fmaxf(a[0], -24.0f), 24.0f);
    a[1] = fminf(fmaxf(a[1], -24.0f), 24.0f);
    float2v Ec  = exp2v(a);                  // e^{2c}
    float2v den = (1.0f + eo) * (1.0f + Ec);
    float   rQ  = __builtin_amdgcn_rcpf(den[0] * den[1]);
    float2v dsw; dsw[0] = den[1]; dsw[1] = den[0];
    return (Ec - 1.0f) * dsw * rQ;           // sigma(o) * tanh(c)
}

// lgkmcnt-only barrier: LDS stores must be visible, but in-flight global
// loads (x prefetch) may cross; their use is vmcnt-guarded by the compiler.
#define BARRIER() asm volatile("s_waitcnt lgkmcnt(0)\n\ts_barrier" ::: "memory")

__global__ __launch_bounds__(256, 2) void lstm_fused(
    const float* __restrict__ x,
    const float* __restrict__ W_ih,
    const float* __restrict__ W_hh,
    const float* __restrict__ b_ih,
    const float* __restrict__ b_hh,
    const float* __restrict__ W_lin,
    const float* __restrict__ b_lin,
    float* __restrict__ out)
{
    __shared__ __align__(16) _Float16 hbuf[2][BPB][HSTR];

    const int tid  = threadIdx.x;
    const int wave = tid >> 6;
    const int lane = tid & 63;
    const int col  = lane & 15;
    const int quad = lane >> 4;
    const int b0   = blockIdx.x * BPB;
    const int j    = wave * 16 + col;
    const bool hiprio = (blockIdx.x & 1) != 0;

    // ---- init h buffers: zeros, x_0 at col 50, 1.0 at col 51 ----
    for (int i = tid; i < 2 * BPB * HSTR; i += 256)
        (&hbuf[0][0][0])[i] = (_Float16)0.0f;
    __syncthreads();
    if (tid < BPB) {
        hbuf[0][tid][HID]     = (_Float16)x[(size_t)(b0 + tid) * NSTEP];
        hbuf[0][tid][HID + 1] = (_Float16)1.0f;
        hbuf[1][tid][HID + 1] = (_Float16)1.0f;
    }

    // ---- persistent B fragments, prescaled per gate ----
    const float LOG2E = 1.4426950408889634f;
    half8 bfrag[4][2];
    for (int g = 0; g < 4; ++g) {
        const float sc = (g == 2) ? (2.0f * LOG2E) : (-LOG2E);
        for (int kt = 0; kt < 2; ++kt) {
            half8 f;
            #pragma unroll
            for (int jj = 0; jj < 8; ++jj) {
                int k = kt * 32 + quad * 8 + jj;
                float v = 0.0f;
                if (j < HID) {
                    int row = g * HID + j;
                    if (k < HID)           v = W_hh[row * HID + k];
                    else if (k == HID)     v = W_ih[row];
                    else if (k == HID + 1) v = b_ih[row] + b_hh[row];
                }
                f[jj] = (_Float16)(v * sc);
            }
            bfrag[g][kt] = f;
        }
    }

    float2v c01 = {0.f, 0.f};
    float2v c23 = {0.f, 0.f};
    const bool xloader = (wave == 3) && (quad == 0);
    const float* xrow = x + (size_t)(b0 + col) * NSTEP;
    const float4v Z4 = {0.f, 0.f, 0.f, 0.f};

    // prefetch x[1] for step 0's store (depth-2 pipeline)
    float xn_reg = 0.f;
    if (xloader)
        xn_reg = xrow[1 < NSTEP ? 1 : NSTEP - 1];

    __syncthreads();

    // ---- persistent priority asymmetry: odd blocks always prio 1 ----
    if (hiprio)
        __builtin_amdgcn_s_setprio(1);

#define STEP(CUR, NXT, T)                                                        \
    {                                                                            \
        /* store pre-loaded x[T+1] early; issue load of x[T+2] */                \
        if (xloader)                                                             \
            hbuf[NXT][col][HID] = (_Float16)xn_reg;                              \
        float xn_new = 0.f;                                                      \
        if (xloader) {                                                           \
            int tt = (T) + 2;                                                    \
            if (tt > NSTEP - 1) tt = NSTEP - 1;                                  \
            xn_new = xrow[tt];                                                   \
        }                                                                        \
        const _Float16* arow = &hbuf[CUR][col][0];                               \
        half8 a0 = *(const half8*)(arow + quad * 8);                             \
        half8 a1 = *(const half8*)(arow + 32 + quad * 8);                        \
        float4v d0, d1, d2, d3;                                                  \
        d0 = __builtin_amdgcn_mfma_f32_16x16x32_f16(a0, bfrag[0][0], Z4, 0, 0, 0); \
        d1 = __builtin_amdgcn_mfma_f32_16x16x32_f16(a0, bfrag[1][0], Z4, 0, 0, 0); \
        d2 = __builtin_amdgcn_mfma_f32_16x16x32_f16(a0, bfrag[2][0], Z4, 0, 0, 0); \
        d3 = __builtin_amdgcn_mfma_f32_16x16x32_f16(a0, bfrag[3][0], Z4, 0, 0, 0); \
        d0 = __builtin_amdgcn_mfma_f32_16x16x32_f16(a1, bfrag[0][1], d0, 0, 0, 0); \
        d1 = __builtin_amdgcn_mfma_f32_16x16x32_f16(a1, bfrag[1][1], d1, 0, 0, 0); \
        d2 = __builtin_amdgcn_mfma_f32_16x16x32_f16(a1, bfrag[2][1], d2, 0, 0, 0); \
        d3 = __builtin_amdgcn_mfma_f32_16x16x32_f16(a1, bfrag[3][1], d3, 0, 0, 0); \
        __builtin_amdgcn_s_setprio(1);                                           \
        /* interleave: gates(lo) -> store -> gates(hi) -> store */               \
        float2v h01 = gate_pairs2(lo2(d0), lo2(d1), lo2(d2), lo2(d3), c01);      \
        if (j < HID) {                                                           \
            hbuf[NXT][quad * 4 + 0][j] = (_Float16)h01[0];                       \
            hbuf[NXT][quad * 4 + 1][j] = (_Float16)h01[1];                       \
        }                                                                        \
        float2v h23 = gate_pairs2(hi2(d0), hi2(d1), hi2(d2), hi2(d3), c23);      \
        if (j < HID) {                                                           \
            hbuf[NXT][quad * 4 + 2][j] = (_Float16)h23[0];                       \
            hbuf[NXT][quad * 4 + 3][j] = (_Float16)h23[1];                       \
        }                                                                        \
        if (!hiprio)                                                             \
            __builtin_amdgcn_s_setprio(0);                                       \
        xn_reg = xn_new;                                                         \
        BARRIER();                                                               \
    }

    for (int t = 0; t < NSTEP; t += 2) {
        STEP(0, 1, t)
        STEP(1, 0, t + 1)
    }
#undef STEP

    // ---- epilogue: out[b] = h_last . W_lin + b_lin ; final h is in hbuf[0] ----
    if (tid < BPB) {
        float s = b_lin[0];
        for (int k = 0; k < HID; ++k)
            s += (float)hbuf[0][tid][k] * W_lin[k];
        out[b0 + tid] = s;
    }
}

extern "C" void kernel_launch(void* const* d_in, const int* in_sizes, int n_in,
                              void* d_out, int out_size, void* d_ws, size_t ws_size,
                              hipStream_t stream) {
    const float* x     = (const float*)d_in[0];
    const float* W_ih  = (const float*)d_in[1];
    const float* W_hh  = (const float*)d_in[2];
    const float* b_ih  = (const float*)d_in[3];
    const float* b_hh  = (const float*)d_in[4];
    const float* W_lin = (const float*)d_in[5];
    const float* b_lin = (const float*)d_in[6];
    float* outp = (float*)d_out;
    dim3 grid(8192 / BPB), block(256);
    hipLaunchKernelGGL(lstm_fused, grid, block, 0, stream,
                       x, W_ih, W_hh, b_ih, b_hh, W_lin, b_lin, outp);
}

// Round 10
// 1258.320 us; speedup vs baseline: 1.2566x; 1.0158x over previous
//
#include <hip/hip_runtime.h>

// OnlineLSTM: B=8192, T=2048, I=1, H=50.
// R14 = exact R11 revert (best measured: 1255 us; R13's lgkm-barrier +
// persistent-prio both reverted after measuring 1278) + LDS XOR-SWIZZLE on
// hbuf to kill the h-store bank conflicts (SQ_LDS_BANK_CONFLICT 3.46e7).
// Row stride 72 fp16 = 36 dwords == 4 (mod 32), so rows 8 apart alias banks
// (8*36 == 0 mod 32): h-store quads 0/2 and 1/3 are a 4-way conflict every
// step. No 16B-aligned pad fixes 8*S == 0 (mod 32); instead: physical elem =
// logical elem ^ 16 for rows 8-15 (32B granule swap), applied to BOTH store
// and read addresses (both-sides-or-neither). Store spans become disjoint
// per quad (pure 2-way = free); b128 A-frag reads stay at the structural
// minimum; all swizzle offsets loop-invariant -> zero added issue.
// Everything else bit-identical to R11: block = 16 rows, 4 waves, grid 512 =
// 2 blocks/CU, gate-major N=256 MFMA, K padded 50->64 (k=50 x_t, k=51 1.0),
// weights prescaled -log2e (i,f,o) / +2log2e (g), packed-fp32 gates,
// x-prefetch depth 2, store/gate interleave, gate setprio, one-shot
// anti-phase s_sleep for odd blocks, plain __syncthreads.

#define HID   50
#define NSTEP 2048
#define BPB   16
#define HSTR  72     // fp16 elems per hbuf row

typedef _Float16 half8   __attribute__((ext_vector_type(8)));
typedef float    float4v __attribute__((ext_vector_type(4)));
typedef float    float2v __attribute__((ext_vector_type(2)));

__device__ __forceinline__ float2v lo2(float4v v) { float2v r; r[0] = v[0]; r[1] = v[1]; return r; }
__device__ __forceinline__ float2v hi2(float4v v) { float2v r; r[0] = v[2]; r[1] = v[3]; return r; }

__device__ __forceinline__ float2v exp2v(float2v x) {
    float2v r;
    r[0] = __builtin_amdgcn_exp2f(x[0]);
    r[1] = __builtin_amdgcn_exp2f(x[1]);
    return r;
}

// Two rows at once. zi,zf,zo = -log2e * raw; zg = 2log2e * raw (prescaled in
// weights). Returns h pair, updates c pair. Packed fp32 algebra; one rcp per
// division pair via rcp(D0*D1) * swapped-D trick.
__device__ __forceinline__ float2v gate_pairs2(float2v zi, float2v zf, float2v zg,
                                               float2v zo, float2v& c) {
    float2v ei = exp2v(zi);      // e^{-i_raw}
    float2v ef = exp2v(zf);
    float2v Eg = exp2v(zg);      // e^{2 g_raw}
    float2v eo = exp2v(zo);
    float2v t1  = (1.0f + ei) * (1.0f + Eg);
    float2v pf  = 1.0f + ef;
    float2v num = c * t1 + pf * (Eg - 1.0f);
    float2v D   = t1 * pf;
    float   rP  = __builtin_amdgcn_rcpf(D[0] * D[1]);
    float2v Dsw; Dsw[0] = D[1]; Dsw[1] = D[0];
    c = num * Dsw * rP;
    float2v a = 2.8853900817779268f * c;     // 2*log2e * c
    a[0] = fminf(fmaxf(a[0], -24.0f), 24.0f);
    a[1] = fminf(fmaxf(a[1], -24.0f), 24.0f);
    float2v Ec  = exp2v(a);                  // e^{2c}
    float2v den = (1.0f + eo) * (1.0f + Ec);
    float   rQ  = __builtin_amdgcn_rcpf(den[0] * den[1]);
    float2v dsw; dsw[0] = den[1]; dsw[1] = den[0];
    return (Ec - 1.0f) * dsw * rQ;           // sigma(o) * tanh(c)
}

__global__ __launch_bounds__(256, 2) void lstm_fused(
    const float* __restrict__ x,
    const float* __restrict__ W_ih,
    const float* __restrict__ W_hh,
    const float* __restrict__ b_ih,
    const float* __restrict__ b_hh,
    const float* __restrict__ W_lin,
    const float* __restrict__ b_lin,
    float* __restrict__ out)
{
    __shared__ __align__(16) _Float16 hbuf[2][BPB][HSTR];

    const int tid  = threadIdx.x;
    const int wave = tid >> 6;
    const int lane = tid & 63;
    const int col  = lane & 15;
    const int quad = lane >> 4;
    const int b0   = blockIdx.x * BPB;
    const int j    = wave * 16 + col;

    // XOR-swizzle: physical elem = logical elem ^ 16 for rows 8-15.
    const int rsw_col = (col & 8) ? 16 : 0;     // swizzle for row index = col
    const int ssw     = (quad >= 2) ? 16 : 0;   // store rows quad*4+r: bit3 = quad>=2

    // ---- init h buffers: zeros, x_0 at (swizzled) col 50, 1.0 at col 51 ----
    for (int i = tid; i < 2 * BPB * HSTR; i += 256)
        (&hbuf[0][0][0])[i] = (_Float16)0.0f;
    __syncthreads();
    if (tid < BPB) {
        int sw = (tid & 8) ? 16 : 0;
        hbuf[0][tid][HID ^ sw]       = (_Float16)x[(size_t)(b0 + tid) * NSTEP];
        hbuf[0][tid][(HID + 1) ^ sw] = (_Float16)1.0f;
        hbuf[1][tid][(HID + 1) ^ sw] = (_Float16)1.0f;
    }

    // ---- persistent B fragments, prescaled per gate ----
    const float LOG2E = 1.4426950408889634f;
    half8 bfrag[4][2];
    for (int g = 0; g < 4; ++g) {
        const float sc = (g == 2) ? (2.0f * LOG2E) : (-LOG2E);
        for (int kt = 0; kt < 2; ++kt) {
            half8 f;
            #pragma unroll
            for (int jj = 0; jj < 8; ++jj) {
                int k = kt * 32 + quad * 8 + jj;
                float v = 0.0f;
                if (j < HID) {
                    int row = g * HID + j;
                    if (k < HID)           v = W_hh[row * HID + k];
                    else if (k == HID)     v = W_ih[row];
                    else if (k == HID + 1) v = b_ih[row] + b_hh[row];
                }
                f[jj] = (_Float16)(v * sc);
            }
            bfrag[g][kt] = f;
        }
    }

    float2v c01 = {0.f, 0.f};
    float2v c23 = {0.f, 0.f};
    const bool xloader = (wave == 3) && (quad == 0);
    const float* xrow = x + (size_t)(b0 + col) * NSTEP;
    const float4v Z4 = {0.f, 0.f, 0.f, 0.f};

    // loop-invariant swizzled offsets
    const int off0 = (quad * 8) ^ rsw_col;      // a0 elem offset within row
    const int xoff = HID ^ rsw_col;             // x-store elem (row = col)

    // prefetch x[1] for step 0's store (depth-2 pipeline)
    float xn_reg = 0.f;
    if (xloader)
        xn_reg = xrow[1 < NSTEP ? 1 : NSTEP - 1];

    __syncthreads();

    // ---- anti-phase stagger: odd blocks start ~960 cyc late ----
    if (blockIdx.x & 1) {
        __builtin_amdgcn_s_sleep(15);
    }

#define STEP(CUR, NXT, T)                                                        \
    {                                                                            \
        /* store pre-loaded x[T+1] early; issue load of x[T+2] */                \
        if (xloader)                                                             \
            hbuf[NXT][col][xoff] = (_Float16)xn_reg;                             \
        float xn_new = 0.f;                                                      \
        if (xloader) {                                                           \
            int tt = (T) + 2;                                                    \
            if (tt > NSTEP - 1) tt = NSTEP - 1;                                  \
            xn_new = xrow[tt];                                                   \
        }                                                                        \
        const _Float16* arow = &hbuf[CUR][col][0];                               \
        half8 a0 = *(const half8*)(arow + off0);                                 \
        half8 a1 = *(const half8*)(arow + 32 + off0);                            \
        float4v d0, d1, d2, d3;                                                  \
        d0 = __builtin_amdgcn_mfma_f32_16x16x32_f16(a0, bfrag[0][0], Z4, 0, 0, 0); \
        d1 = __builtin_amdgcn_mfma_f32_16x16x32_f16(a0, bfrag[1][0], Z4, 0, 0, 0); \
        d2 = __builtin_amdgcn_mfma_f32_16x16x32_f16(a0, bfrag[2][0], Z4, 0, 0, 0); \
        d3 = __builtin_amdgcn_mfma_f32_16x16x32_f16(a0, bfrag[3][0], Z4, 0, 0, 0); \
        d0 = __builtin_amdgcn_mfma_f32_16x16x32_f16(a1, bfrag[0][1], d0, 0, 0, 0); \
        d1 = __builtin_amdgcn_mfma_f32_16x16x32_f16(a1, bfrag[1][1], d1, 0, 0, 0); \
        d2 = __builtin_amdgcn_mfma_f32_16x16x32_f16(a1, bfrag[2][1], d2, 0, 0, 0); \
        d3 = __builtin_amdgcn_mfma_f32_16x16x32_f16(a1, bfrag[3][1], d3, 0, 0, 0); \
        __builtin_amdgcn_s_setprio(1);                                           \
        /* interleave: gates(lo) -> store -> gates(hi) -> store */               \
        float2v h01 = gate_pairs2(lo2(d0), lo2(d1), lo2(d2), lo2(d3), c01);      \
        if (j < HID) {                                                           \
            hbuf[NXT][quad * 4 + 0][j ^ ssw] = (_Float16)h01[0];                 \
            hbuf[NXT][quad * 4 + 1][j ^ ssw] = (_Float16)h01[1];                 \
        }                                                                        \
        float2v h23 = gate_pairs2(hi2(d0), hi2(d1), hi2(d2), hi2(d3), c23);      \
        if (j < HID) {                                                           \
            hbuf[NXT][quad * 4 + 2][j ^ ssw] = (_Float16)h23[0];                 \
            hbuf[NXT][quad * 4 + 3][j ^ ssw] = (_Float16)h23[1];                 \
        }                                                                        \
        __builtin_amdgcn_s_setprio(0);                                           \
        xn_reg = xn_new;                                                         \
        __syncthreads();                                                         \
    }

    for (int t = 0; t < NSTEP; t += 2) {
        STEP(0, 1, t)
        STEP(1, 0, t + 1)
    }
#undef STEP

    // ---- epilogue: out[b] = h_last . W_lin + b_lin ; final h is in hbuf[0] ----
    if (tid < BPB) {
        int sw = (tid & 8) ? 16 : 0;
        float s = b_lin[0];
        for (int k = 0; k < HID; ++k)
            s += (float)hbuf[0][tid][k ^ sw] * W_lin[k];
        out[b0 + tid] = s;
    }
}

extern "C" void kernel_launch(void* const* d_in, const int* in_sizes, int n_in,
                              void* d_out, int out_size, void* d_ws, size_t ws_size,
                              hipStream_t stream) {
    const float* x     = (const float*)d_in[0];
    const float* W_ih  = (const float*)d_in[1];
    const float* W_hh  = (const float*)d_in[2];
    const float* b_ih  = (const float*)d_in[3];
    const float* b_hh  = (const float*)d_in[4];
    const float* W_lin = (const float*)d_in[5];
    const float* b_lin = (const float*)d_in[6];
    float* outp = (float*)d_out;
    dim3 grid(8192 / BPB), block(256);
    hipLaunchKernelGGL(lstm_fused, grid, block, 0, stream,
                       x, W_ih, W_hh, b_ih, b_hh, W_lin, b_lin, outp);
}